// Round 20
// baseline (427.270 us; speedup 1.0000x reference)
//
#include <hip/hip_runtime.h>
#include <hip/hip_bf16.h>
#include <stdint.h>
#include <stddef.h>

using bf16 = __hip_bfloat16;

typedef __attribute__((ext_vector_type(4))) float f32x4;
typedef __attribute__((ext_vector_type(8))) short bf16x8;
typedef __attribute__((ext_vector_type(4))) unsigned short u16x4;

#define K_DIM 4096
#define M_ROWS 8192
#define BM 256
#define BN 256
#define BK 64
#define NT (K_DIM / BK)      // 64 K-tiles
#define MT2 (M_ROWS / BM)    // 32
#define NT2 (K_DIM / BN)     // 16

// ---------------------------------------------------------------------------
// Kernel 1: f32 -> bf16 conversion (vectorized, grid-stride)
// ---------------------------------------------------------------------------
__global__ void conv_bf16(const float* __restrict__ in, bf16* __restrict__ outb, int n4) {
  int idx = blockIdx.x * blockDim.x + threadIdx.x;
  int stride = gridDim.x * blockDim.x;
  for (int k = idx; k < n4; k += stride) {
    f32x4 v = ((const f32x4*)in)[k];
    bf16 tmp[4];
    tmp[0] = __float2bfloat16(v.x);
    tmp[1] = __float2bfloat16(v.y);
    tmp[2] = __float2bfloat16(v.z);
    tmp[3] = __float2bfloat16(v.w);
    ((u16x4*)outb)[k] = *(const u16x4*)tmp;
  }
}

// ---------------------------------------------------------------------------
// Kernel 2: build G^T in bf16 (verified round 1).
// ---------------------------------------------------------------------------
__global__ void build_gt(const float* __restrict__ core0, const float* __restrict__ core1,
                         bf16* __restrict__ GT) {
  int j = blockIdx.x >> 6;
  int i = blockIdx.x & 63;
  __shared__ float c0s[64][16];
  __shared__ float c1s[64][16];
  int t = threadIdx.x;
#pragma unroll
  for (int rep = 0; rep < 4; ++rep) {
    int idx = rep * 256 + t;
    int row = idx >> 4;
    int b = idx & 15;
    size_t base = ((size_t)(j * 64 + row) * 64 + i) * 16 + b;
    c1s[row][b] = core1[base];
    c0s[row][b] = core0[base];
  }
  __syncthreads();
  int x = t & 63;
  int ys = t >> 6;
  float r1[16];
#pragma unroll
  for (int b = 0; b < 16; ++b) r1[b] = c1s[x][b];
#pragma unroll
  for (int yy = 0; yy < 16; ++yy) {
    int y = ys * 16 + yy;
    float acc = 0.f;
#pragma unroll
    for (int b = 0; b < 16; ++b) acc += r1[b] * c0s[y][b];
    GT[((size_t)(y * 64 + i) << 12) + (size_t)(j * 64 + x)] = __float2bfloat16(acc);
  }
}

// ---------------------------------------------------------------------------
// Kernel 3: FAT-WAVE decomposition (R19 retry; LDS-pointer-array replaced by
// base+offset arithmetic to fix the gfx950 static-initializer addrspacecast
// compile error). 256x256 tile / BK=64 / 4 waves, wave tile 128x128 ->
// LDS reads/MFMA 0.25: per CU per tile LDS=1536 < MFMA=2483 cyc -> MFMA-bound.
// 1 wave/SIMD. Zero intra-tile barriers; compiler-counted lgkm waits each
// pre-drained under a 32-MFMA burst. 1 vmcnt(0)+barrier per tile.
// ---------------------------------------------------------------------------
__device__ __forceinline__ void gload_lds16(const bf16* g, bf16* l) {
  __builtin_amdgcn_global_load_lds(
      (const __attribute__((address_space(1))) unsigned int*)(g),
      (__attribute__((address_space(3))) unsigned int*)(l),
      16, 0, 0);
}

#define BARRIER() asm volatile("s_barrier" ::: "memory")
#define VMCNT0() asm volatile("s_waitcnt vmcnt(0)" ::: "memory")
#define SP1() __builtin_amdgcn_s_setprio(1)
#define SP0() __builtin_amdgcn_s_setprio(0)

__global__ __launch_bounds__(256, 1)
void gemm_xg(const bf16* __restrict__ Xb, const bf16* __restrict__ GT,
             const float* __restrict__ bias, float* __restrict__ out) {
  __shared__ bf16 As[2][BM * BK];   // 2 x 32 KiB
  __shared__ bf16 Bs[2][BN * BK];   // 2 x 32 KiB  (128 KiB total)

  // XCD-aware swizzle: nwg = 512, divisible by 8
  int bid = blockIdx.x;
  int sb = (bid & 7) * (MT2 * NT2 / 8) + (bid >> 3);
  int bm = sb >> 4;
  int bn = sb & 15;

  int t = threadIdx.x;
  int lane = t & 63;
  int wid = t >> 6;          // 0..3

  // ---- staging addressing (linear LDS dest, inverse-swizzled global src) ----
  int srow = t >> 3;                    // 0..31
  int scol = t & 7;                     // dest 16B slot (linear)
  int sxor = scol ^ (srow & 7);         // pre-swizzled global slot
  const bf16* gA0 = Xb + ((size_t)(bm * BM + srow) * K_DIM) + sxor * 8;
  const bf16* gB0 = GT + ((size_t)(bn * BN + srow) * K_DIM) + sxor * 8;
  int lbase = srow * BK + scol * 8;

  bf16* As0 = &As[0][0];
  bf16* Bs0 = &Bs[0][0];

  auto stage = [&](int buf, int kt) {
    bf16* la = As0 + buf * (BM * BK) + lbase;
    bf16* lb = Bs0 + buf * (BN * BK) + lbase;
#pragma unroll
    for (int h = 0; h < 8; ++h)
      gload_lds16(gA0 + (size_t)(h * 32) * K_DIM + (size_t)kt * BK,
                  la + h * 32 * BK);
#pragma unroll
    for (int h = 0; h < 8; ++h)
      gload_lds16(gB0 + (size_t)(h * 32) * K_DIM + (size_t)kt * BK,
                  lb + h * 32 * BK);
  };

  // ---- fragment addressing (swizzled ds_read; champion pattern) ----
  int wm = wid >> 1;        // 0..1
  int wn = wid & 1;         // 0..1
  int lr = lane & 15;
  int g4 = lane >> 4;
  int x7 = lr & 7;
  int swk0 = ((g4 ^ x7) << 3);
  int swk1 = (((4 + g4) ^ x7) << 3);
  int abase = (wm * 128 + lr) * BK;     // wave A-panel: 128 rows
  int bbase = (wn * 128 + lr) * BK;     // wave B-panel: 128 rows

  f32x4 acc[8][8] = {};                 // 256 VGPR
  bf16x8 a0[4][2], a1[4][2];            // A mi-halves (mi 0-3 / 4-7)
  bf16x8 b0[4][2], b1[4][2];            // B ni-halves (ni 0-3 / 4-7)

  auto rdA = [&](bf16x8 (&av)[4][2], const bf16* Ap, int half) {
#pragma unroll
    for (int mi = 0; mi < 4; ++mi) {
      int off = abase + (half * 4 + mi) * 1024;
      av[mi][0] = *(const bf16x8*)&Ap[off + swk0];
      av[mi][1] = *(const bf16x8*)&Ap[off + swk1];
    }
  };
  auto rdB = [&](bf16x8 (&bv)[4][2], const bf16* Bp, int half) {
#pragma unroll
    for (int ni = 0; ni < 4; ++ni) {
      int off = bbase + (half * 4 + ni) * 1024;
      bv[ni][0] = *(const bf16x8*)&Bp[off + swk0];
      bv[ni][1] = *(const bf16x8*)&Bp[off + swk1];
    }
  };
  auto MQ = [&](int mh, int nh, bf16x8 (&av)[4][2], bf16x8 (&bv)[4][2]) {
    SP1();
#pragma unroll
    for (int kk = 0; kk < 2; ++kk)
#pragma unroll
      for (int mi = 0; mi < 4; ++mi)
#pragma unroll
        for (int ni = 0; ni < 4; ++ni)
          acc[mh * 4 + mi][nh * 4 + ni] = __builtin_amdgcn_mfma_f32_16x16x32_bf16(
              av[mi][kk], bv[ni][kk], acc[mh * 4 + mi][nh * 4 + ni], 0, 0, 0);
    SP0();
  };

  // ---- prologue: stage tile 0; certify for all waves ----
  stage(0, 0);
  VMCNT0();
  BARRIER();

  // ---- main loop: zero intra-tile barriers ----
#pragma unroll 1
  for (int kt = 0; kt < NT; ++kt) {
    int cur = kt & 1;
    const bf16* Ac = As0 + cur * (BM * BK);
    const bf16* Bc = Bs0 + cur * (BN * BK);

    if (kt + 1 < NT) stage(cur ^ 1, kt + 1);   // issue early; drained at tile end

    rdA(a0, Ac, 0);
    rdB(b0, Bc, 0);
    rdA(a1, Ac, 1);
    MQ(0, 0, a0, b0);     // waits a0,b0 (counted; a1 drains under this burst)
    rdB(b1, Bc, 1);
    MQ(1, 0, a1, b0);     // waits a1 (counted; b1 drains under this burst)
    MQ(0, 1, a0, b1);     // waits b1 -> all reads of buf[cur] retired
    MQ(1, 1, a1, b1);

    VMCNT0();             // own stage(kt+1) landed (issued ~full tile earlier)
    BARRIER();            // collective: next tile's reads + buf reuse safe
  }

  // ---- epilogue: C/D layout col = lane&15, row = (lane>>4)*4 + r ----
  int colbase = bn * BN + wn * 128 + lr;
  int rowbase = bm * BM + wm * 128 + g4 * 4;
#pragma unroll
  for (int ni = 0; ni < 8; ++ni) {
    int col = colbase + ni * 16;
    float bv = bias[col];
#pragma unroll
    for (int mi = 0; mi < 8; ++mi) {
#pragma unroll
      for (int r = 0; r < 4; ++r) {
        int row = rowbase + mi * 16 + r;
        out[(size_t)row * K_DIM + col] = acc[mi][ni][r] + bv;
      }
    }
  }
}

// ---------------------------------------------------------------------------
extern "C" void kernel_launch(void* const* d_in, const int* in_sizes, int n_in,
                              void* d_out, int out_size, void* d_ws, size_t ws_size,
                              hipStream_t stream) {
  const float* x     = (const float*)d_in[0];
  const float* core0 = (const float*)d_in[1];
  const float* core1 = (const float*)d_in[2];
  const float* bias  = (const float*)d_in[3];
  float* out = (float*)d_out;

  bf16* Xb = (bf16*)d_ws;
  bf16* GT = (bf16*)((char*)d_ws + (size_t)M_ROWS * K_DIM * sizeof(bf16));

  conv_bf16<<<2048, 256, 0, stream>>>(x, Xb, (M_ROWS * K_DIM) / 4);
  build_gt<<<4096, 256, 0, stream>>>(core0, core1, GT);
  gemm_xg<<<MT2 * NT2, 256, 0, stream>>>(Xb, GT, bias, out);
}

// Round 21
// 284.025 us; speedup vs baseline: 1.5043x; 1.5043x over previous
//
#include <hip/hip_runtime.h>
#include <hip/hip_bf16.h>
#include <stdint.h>
#include <stddef.h>

using bf16 = __hip_bfloat16;

typedef __attribute__((ext_vector_type(4))) float f32x4;
typedef __attribute__((ext_vector_type(8))) short bf16x8;
typedef __attribute__((ext_vector_type(4))) unsigned short u16x4;

#define K_DIM 4096
#define M_ROWS 8192
#define BM 256
#define BN 256
#define BK 64
#define NT (K_DIM / BK)      // 64 K-tiles
#define MT2 (M_ROWS / BM)    // 32
#define NT2 (K_DIM / BN)     // 16

template<int M> struct MC { static constexpr int value = M; };

// ---------------------------------------------------------------------------
// Kernel 1: f32 -> bf16 conversion (vectorized, grid-stride)
// ---------------------------------------------------------------------------
__global__ void conv_bf16(const float* __restrict__ in, bf16* __restrict__ outb, int n4) {
  int idx = blockIdx.x * blockDim.x + threadIdx.x;
  int stride = gridDim.x * blockDim.x;
  for (int k = idx; k < n4; k += stride) {
    f32x4 v = ((const f32x4*)in)[k];
    bf16 tmp[4];
    tmp[0] = __float2bfloat16(v.x);
    tmp[1] = __float2bfloat16(v.y);
    tmp[2] = __float2bfloat16(v.z);
    tmp[3] = __float2bfloat16(v.w);
    ((u16x4*)outb)[k] = *(const u16x4*)tmp;
  }
}

// ---------------------------------------------------------------------------
// Kernel 2: build G^T in bf16 (verified round 1).
// ---------------------------------------------------------------------------
__global__ void build_gt(const float* __restrict__ core0, const float* __restrict__ core1,
                         bf16* __restrict__ GT) {
  int j = blockIdx.x >> 6;
  int i = blockIdx.x & 63;
  __shared__ float c0s[64][16];
  __shared__ float c1s[64][16];
  int t = threadIdx.x;
#pragma unroll
  for (int rep = 0; rep < 4; ++rep) {
    int idx = rep * 256 + t;
    int row = idx >> 4;
    int b = idx & 15;
    size_t base = ((size_t)(j * 64 + row) * 64 + i) * 16 + b;
    c1s[row][b] = core1[base];
    c0s[row][b] = core0[base];
  }
  __syncthreads();
  int x = t & 63;
  int ys = t >> 6;
  float r1[16];
#pragma unroll
  for (int b = 0; b < 16; ++b) r1[b] = c1s[x][b];
#pragma unroll
  for (int yy = 0; yy < 16; ++yy) {
    int y = ys * 16 + yy;
    float acc = 0.f;
#pragma unroll
    for (int b = 0; b < 16; ++b) acc += r1[b] * c0s[y][b];
    GT[((size_t)(y * 64 + i) << 12) + (size_t)(j * 64 + x)] = __float2bfloat16(acc);
  }
}

// ---------------------------------------------------------------------------
// Kernel 3 (CHAMPION, R15/R18-verified): 256x256 / BK=64 / 8-wave, phase order
//   reads -> stage -> lgkm(0) -> barrier -> MFMA(regs-only)
// 1 barrier/phase (ph3 none). lgkm(0) BEFORE the barrier closes the
// cross-wave read-vs-stage race; MFMA after the barrier is register-only.
// vmcnt(4)/tile at ph0 (drains A(t),B(t); keeps B(t+1) in flight).
// Measured twice: GEMM 262-266 us, ~1045 TF, MfmaUtil 46.9%, conflicts 0.
// ---------------------------------------------------------------------------
__device__ __forceinline__ void gload_lds16(const bf16* g, bf16* l) {
  __builtin_amdgcn_global_load_lds(
      (const __attribute__((address_space(1))) unsigned int*)(g),
      (__attribute__((address_space(3))) unsigned int*)(l),
      16, 0, 0);
}

template<int MH>
__device__ __forceinline__ void read_a(bf16x8 (&af)[4][2], const bf16* As,
                                       int abase, int swk0, int swk1) {
#pragma unroll
  for (int mi = 0; mi < 4; ++mi) {
    int off = abase + (MH * 4 + mi) * 1024;   // 16 rows * 64 elem
    af[mi][0] = *(const bf16x8*)&As[off + swk0];
    af[mi][1] = *(const bf16x8*)&As[off + swk1];
  }
}

template<int NH>
__device__ __forceinline__ void read_b(bf16x8 (&bfr)[4][2], const bf16* Bs,
                                       int bbase, int swk0, int swk1) {
#pragma unroll
  for (int ni = 0; ni < 2; ++ni) {
    int off = bbase + (NH * 2 + ni) * 1024;
    bfr[NH * 2 + ni][0] = *(const bf16x8*)&Bs[off + swk0];
    bfr[NH * 2 + ni][1] = *(const bf16x8*)&Bs[off + swk1];
  }
}

template<int MH, int NH>
__device__ __forceinline__ void mfma_quad(f32x4 (&acc)[8][4], const bf16x8 (&af)[4][2],
                                          const bf16x8 (&bfr)[4][2]) {
#pragma unroll
  for (int kk = 0; kk < 2; ++kk)
#pragma unroll
    for (int mi = 0; mi < 4; ++mi)
#pragma unroll
      for (int ni = 0; ni < 2; ++ni)
        acc[MH * 4 + mi][NH * 2 + ni] = __builtin_amdgcn_mfma_f32_16x16x32_bf16(
            af[mi][kk], bfr[NH * 2 + ni][kk], acc[MH * 4 + mi][NH * 2 + ni], 0, 0, 0);
}

#define BARRIER() asm volatile("s_barrier" ::: "memory")
#define LGKM0() asm volatile("s_waitcnt lgkmcnt(0)" ::: "memory")
#define SP1() __builtin_amdgcn_s_setprio(1)
#define SP0() __builtin_amdgcn_s_setprio(0)
#define VMCNT4() asm volatile("s_waitcnt vmcnt(4)" ::: "memory")
#define VMCNT0() asm volatile("s_waitcnt vmcnt(0)" ::: "memory")

__global__ __launch_bounds__(512, 2)
void gemm_xg(const bf16* __restrict__ Xb, const bf16* __restrict__ GT,
             const float* __restrict__ bias, float* __restrict__ out) {
  __shared__ bf16 As[2][BM * BK];   // 2 x 32 KiB
  __shared__ bf16 Bs[2][BN * BK];   // 2 x 32 KiB

  // XCD-aware swizzle: nwg = 512, divisible by 8
  int bid = blockIdx.x;
  int sb = (bid & 7) * (MT2 * NT2 / 8) + (bid >> 3);
  int bm = sb >> 4;
  int bn = sb & 15;

  int t = threadIdx.x;
  int lane = t & 63;
  int wid = t >> 6;

  // ---- staging addressing (linear LDS dest, inverse-swizzled global src) ----
  int srow = t >> 3;                    // 0..63
  int scol = t & 7;                     // dest 16B slot (linear)
  int sxor = scol ^ (srow & 7);         // pre-swizzled global slot
  const bf16* gA0 = Xb + ((size_t)(bm * BM + srow) * K_DIM) + sxor * 8;
  const bf16* gB0 = GT + ((size_t)(bn * BN + srow) * K_DIM) + sxor * 8;
  int lbase = srow * BK + scol * 8;

  auto sA = [&](int buf, int h, int kt) {
    const bf16* g = gA0 + (size_t)(h * 128) * K_DIM + (size_t)kt * BK;
    bf16* l = &As[buf][h * 128 * BK + lbase];
    gload_lds16(g, l);
    gload_lds16(g + (size_t)64 * K_DIM, l + 64 * BK);
  };
  auto sB = [&](int buf, int h, int kt) {
    const bf16* g = gB0 + (size_t)(h * 128) * K_DIM + (size_t)kt * BK;
    bf16* l = &Bs[buf][h * 128 * BK + lbase];
    gload_lds16(g, l);
    gload_lds16(g + (size_t)64 * K_DIM, l + 64 * BK);
  };

  // ---- fragment addressing (swizzled ds_read) ----
  int wm = wid >> 2;        // 0..1
  int wn = wid & 3;         // 0..3
  int lr = lane & 15;
  int g4 = lane >> 4;
  int x7 = lr & 7;
  int swk0 = ((g4 ^ x7) << 3);
  int swk1 = (((4 + g4) ^ x7) << 3);
  int abase = (wm * 128 + lr) * BK;
  int bbase = (wn * 64 + lr) * BK;

  f32x4 acc[8][4] = {};
  bf16x8 af[4][2];
  bf16x8 bfr[4][2];

  const bf16* Ab[2] = { &As[0][0], &As[1][0] };
  const bf16* Bb[2] = { &Bs[0][0], &Bs[1][0] };

  // ---- per-tile; MODE: 0=steady, 1=t==NT-2 (skip B stages), 2=last ----
  auto tile = [&](int kt, int cur, auto modec) {
    constexpr int MODE = decltype(modec)::value;
    const bf16* Ac = Ab[cur];
    const bf16* Bc = Bb[cur];
    const int nb = cur ^ 1;

    // ph0: Q00 — reads A0(t)+B0(t); stage A(t+1)h0; lgkm; barrier; MFMA
    if (MODE == 2) { VMCNT0(); } else { VMCNT4(); }   // drain A(t),B(t); keep B(t+1)
    read_a<0>(af, Ac, abase, swk0, swk1);
    read_b<0>(bfr, Bc, bbase, swk0, swk1);
    if (MODE < 2) sA(nb, 0, kt + 1);
    LGKM0();
    BARRIER();
    SP1(); mfma_quad<0, 0>(acc, af, bfr); SP0();

    // ph1: Q01 — reads B1(t); stage A(t+1)h1
    read_b<1>(bfr, Bc, bbase, swk0, swk1);
    if (MODE < 2) sA(nb, 1, kt + 1);
    LGKM0();
    BARRIER();
    SP1(); mfma_quad<0, 1>(acc, af, bfr); SP0();

    // ph2: Q10 — reads A1(t); stage B(t+2)h0
    read_a<1>(af, Ac, abase, swk0, swk1);
    if (MODE == 0) sB(cur, 0, kt + 2);
    LGKM0();
    BARRIER();
    SP1(); mfma_quad<1, 0>(acc, af, bfr); SP0();

    // ph3: Q11 — no reads; stage B(t+2)h1; no barrier needed (audited)
    if (MODE == 0) sB(cur, 1, kt + 2);
    SP1(); mfma_quad<1, 1>(acc, af, bfr); SP0();
  };

  // ---- prologue: FIFO order B(0), A(0), B(1); drain tile0, keep B(1) ----
  sB(0, 0, 0); sB(0, 1, 0);
  sA(0, 0, 0); sA(0, 1, 0);
  sB(1, 0, 1); sB(1, 1, 1);
  VMCNT4();
  BARRIER();

#pragma unroll 1
  for (int i = 0; i < NT / 2 - 1; ++i) {
    tile(2 * i,     0, MC<0>{});
    tile(2 * i + 1, 1, MC<0>{});
  }
  tile(NT - 2, 0, MC<1>{});
  tile(NT - 1, 1, MC<2>{});

  // ---- epilogue: C/D layout col = lane&15, row = (lane>>4)*4 + r ----
  int colbase = bn * BN + wn * 64 + lr;
  int rowbase = bm * BM + wm * 128 + g4 * 4;
#pragma unroll
  for (int ni = 0; ni < 4; ++ni) {
    int col = colbase + ni * 16;
    float bv = bias[col];
#pragma unroll
    for (int mi = 0; mi < 8; ++mi) {
#pragma unroll
      for (int r = 0; r < 4; ++r) {
        int row = rowbase + mi * 16 + r;
        out[(size_t)row * K_DIM + col] = acc[mi][ni][r] + bv;
      }
    }
  }
}

// ---------------------------------------------------------------------------
extern "C" void kernel_launch(void* const* d_in, const int* in_sizes, int n_in,
                              void* d_out, int out_size, void* d_ws, size_t ws_size,
                              hipStream_t stream) {
  const float* x     = (const float*)d_in[0];
  const float* core0 = (const float*)d_in[1];
  const float* core1 = (const float*)d_in[2];
  const float* bias  = (const float*)d_in[3];
  float* out = (float*)d_out;

  bf16* Xb = (bf16*)d_ws;
  bf16* GT = (bf16*)((char*)d_ws + (size_t)M_ROWS * K_DIM * sizeof(bf16));

  conv_bf16<<<2048, 256, 0, stream>>>(x, Xb, (M_ROWS * K_DIM) / 4);
  build_gt<<<4096, 256, 0, stream>>>(core0, core1, GT);
  gemm_xg<<<MT2 * NT2, 512, 0, stream>>>(Xb, GT, bias, out);
}